// Round 1
// baseline (481.087 us; speedup 1.0000x reference)
//
#include <hip/hip_runtime.h>

// ConvolutionN: B=64, C=64, H=W=128, K=7, PAD=3, single output channel, fp32.
// Direct conv, LDS-tiled: 128W x 16H output tile per block, loop over 64 channels.
// Double-buffered LDS + register prefetch of next channel; 1 barrier/channel.

#define TB       256
#define TILE_H   16
#define TILE_W   128
#define IN_ROWS  22        // TILE_H + K - 1
#define STRIDE   140       // padded LDS row stride (>=134); conflict-free for b128 pattern
#define NLOAD    13        // ceil(IN_ROWS*STRIDE / TB) = ceil(3080/256)
#define C_CH     64
#define HIMG     128
#define WIMG     128
#define CH_STRIDE (HIMG*WIMG)

__global__ __launch_bounds__(TB, 2)
void conv7x7_c64(const float* __restrict__ x, const float* __restrict__ w,
                 const float* __restrict__ bias, float* __restrict__ out) {
    __shared__ float buf[2][IN_ROWS * STRIDE];

    const int tid = threadIdx.x;
    const int tx  = tid & 15;   // 16 groups across W, 8 px each
    const int ty  = tid >> 4;   // 16 output rows
    const int bx  = blockIdx.x;
    const int b   = bx >> 3;    // batch
    const int t   = bx & 7;     // h-tile
    const int row0 = t * TILE_H;

    // Per-thread staging slots (channel-independent offsets + validity).
    int  offs[NLOAD];
    bool ok[NLOAD];
#pragma unroll
    for (int k = 0; k < NLOAD; k++) {
        int i  = tid + k * TB;
        int r  = i / STRIDE;
        int cc = i - r * STRIDE;
        int gr = row0 + r - 3;
        int gc = cc - 3;
        bool v = (i < IN_ROWS * STRIDE) && (gr >= 0) && (gr < HIMG) &&
                 (gc >= 0) && (gc < WIMG);
        ok[k]   = v;
        offs[k] = v ? gr * WIMG + gc : 0;
    }

    const float* xb = x + (size_t)b * C_CH * CH_STRIDE;

    // Prefetch channel 0 into registers.
    float pre[NLOAD];
#pragma unroll
    for (int k = 0; k < NLOAD; k++) pre[k] = ok[k] ? xb[offs[k]] : 0.f;

    float acc[8];
#pragma unroll
    for (int p = 0; p < 8; p++) acc[p] = 0.f;

    for (int c = 0; c < C_CH; c++) {
        float* bufc = buf[c & 1];
        // Stage channel c from registers into LDS.
#pragma unroll
        for (int k = 0; k < NLOAD; k++) {
            int i = tid + k * TB;
            if (i < IN_ROWS * STRIDE) bufc[i] = pre[k];
        }
        __syncthreads();

        // Issue global loads for channel c+1 (hidden under compute below).
        if (c < C_CH - 1) {
            const float* xn = xb + (size_t)(c + 1) * CH_STRIDE;
#pragma unroll
            for (int k = 0; k < NLOAD; k++) pre[k] = ok[k] ? xn[offs[k]] : 0.f;
        }

        const float* wc = w + c * 49;   // wave-uniform -> scalar loads
#pragma unroll
        for (int dh = 0; dh < 7; dh++) {
            float wv[7];
#pragma unroll
            for (int dw = 0; dw < 7; dw++) wv[dw] = wc[dh * 7 + dw];

            const float4* rp = (const float4*)&bufc[(ty + dh) * STRIDE + 8 * tx];
            float4 q0 = rp[0], q1 = rp[1], q2 = rp[2], q3 = rp[3];
            float v[16] = {q0.x, q0.y, q0.z, q0.w, q1.x, q1.y, q1.z, q1.w,
                           q2.x, q2.y, q2.z, q2.w, q3.x, q3.y, q3.z, q3.w};
#pragma unroll
            for (int dw = 0; dw < 7; dw++)
#pragma unroll
                for (int p = 0; p < 8; p++)
                    acc[p] = fmaf(v[dw + p], wv[dw], acc[p]);
        }
        // No second barrier needed: next iteration writes the OTHER buffer,
        // and the write-after-read hazard on this buffer is fenced by the
        // barrier two iterations ahead (each wave's program order guarantees
        // compute(c) precedes its write(c+1) -> barrier(c+1) -> write(c+2)).
    }

    const float bv = bias[0];
    float4 o0 = make_float4(acc[0] + bv, acc[1] + bv, acc[2] + bv, acc[3] + bv);
    float4 o1 = make_float4(acc[4] + bv, acc[5] + bv, acc[6] + bv, acc[7] + bv);
    float4* op = (float4*)&out[((size_t)b * HIMG + row0 + ty) * WIMG + 8 * tx];
    op[0] = o0;
    op[1] = o1;
}

extern "C" void kernel_launch(void* const* d_in, const int* in_sizes, int n_in,
                              void* d_out, int out_size, void* d_ws, size_t ws_size,
                              hipStream_t stream) {
    const float* x    = (const float*)d_in[0];   // (64,64,128,128)
    const float* w    = (const float*)d_in[1];   // (64,7,7)
    const float* bias = (const float*)d_in[2];   // (1,)
    float* out        = (float*)d_out;           // (64,128,128)

    hipLaunchKernelGGL(conv7x7_c64, dim3(512), dim3(TB), 0, stream, x, w, bias, out);
}

// Round 2
// 453.714 us; speedup vs baseline: 1.0603x; 1.0603x over previous
//
#include <hip/hip_runtime.h>
#include <stdint.h>

// ConvolutionN: B=64, C=64, H=W=128, K=7, PAD=3, one output channel, fp32.
// v2: bf16 LDS staging (half the LDS bytes), R=4 vertical register blocking,
// float2/pk_fma-friendly inner loop, C-split 4 + fp32 atomics for occupancy.
//
// Per-CU cycle model: VALU ~70k cyc/SIMD (pk) or ~114k (scalar fallback),
// LDS ~40k cyc, HBM ~290MB/6.3TB/s = 44us. Target 55-75us.

#define TB       256
#define TILE_H   64
#define IN_ROWS  70          // TILE_H + 6 halo rows
#define ROW_DW   68          // LDS row stride in dwords (136 bf16: 4 left halo + 128 data + 3 right halo + 1 dead)
                             // 68 mod 8 == 4 -> rows 4 apart hit different bank bases (no >8-way conflicts)
#define CPB      16          // channels per block (C-split 4)
#define NSLOT    (IN_ROWS*32) // 2240 4-col staging chunks per channel
#define NLOAD    9           // ceil(2240/256)
#define HIMG     128
#define WIMG     128
#define CH_ELEMS (HIMG*WIMG)

// bf16 truncation pack of two floats into one dword (1x v_perm_b32).
__device__ __forceinline__ uint32_t pk_bf16(float lo, float hi) {
    return __builtin_amdgcn_perm(__builtin_bit_cast(uint32_t, hi),
                                 __builtin_bit_cast(uint32_t, lo), 0x07060302u);
}

__device__ __forceinline__ float bf_lo(uint32_t u) {
    return __builtin_bit_cast(float, u << 16);
}
__device__ __forceinline__ float bf_hi(uint32_t u) {
    return __builtin_bit_cast(float, u & 0xFFFF0000u);
}

// packed-friendly dual fma; SLP should merge into v_pk_fma_f32
__device__ __forceinline__ float2 pkfma(float2 a, float wb, float2 c) {
    return make_float2(fmaf(a.x, wb, c.x), fmaf(a.y, wb, c.y));
}

__global__ __launch_bounds__(TB, 2)
void conv7x7_v2(const float* __restrict__ x, const float* __restrict__ w,
                const float* __restrict__ bias, float* __restrict__ out) {
    __shared__ uint32_t lds[2][IN_ROWS * ROW_DW];   // 2 x 19040 B = 38080 B

    const int tid = threadIdx.x;
    const int tx  = tid & 15;        // 16 col-groups of 8 px
    const int ty  = tid >> 4;        // 16 row-groups of 4 output rows
    const int bx  = blockIdx.x;
    const int cs  = bx & 3;          // channel split 0..3
    const int t   = (bx >> 2) & 1;   // h-tile 0..1
    const int b   = bx >> 3;         // batch
    const int row0 = t * TILE_H;
    const int c0  = cs * CPB;

    // Staging slot geometry (channel-independent): slot s covers LDS row r = s/32,
    // 4-col chunk j = s%32 (global cols 4j..4j+3).
    int g4off[NLOAD];   // float4 index in channel plane, -1 if zero-fill
    int ldso[NLOAD];    // LDS dword offset for the uint2 write
#pragma unroll
    for (int k = 0; k < NLOAD; k++) {
        int s  = tid + k * TB;
        int r  = s >> 5;
        int j  = s & 31;
        int gr = row0 + r - 3;
        bool row_ok = (s < NSLOT) && (gr >= 0) && (gr < HIMG);
        g4off[k] = row_ok ? (gr * 32 + j) : -1;
        ldso[k]  = (s < NSLOT) ? (ROW_DW * r + 2 + 2 * j) : 0;
    }

    // Zero the halo columns of both buffers once (cols -4..-1 -> dwords 0,1;
    // cols 128..130 + dead -> dwords 66,67). Data writes never touch these.
#pragma unroll
    for (int z = 0; z < 2; z++) {
        int s = tid + z * TB;
        if (s < 2 * IN_ROWS * 2) {
            int bufi = (s >= IN_ROWS * 2) ? 1 : 0;
            int rem  = s - bufi * IN_ROWS * 2;
            int r    = rem >> 1;
            int side = rem & 1;
            uint2 zz; zz.x = 0u; zz.y = 0u;
            *(uint2*)&lds[bufi][ROW_DW * r + (side ? 66 : 0)] = zz;
        }
    }

    const float4* xb4 = (const float4*)(x + ((size_t)b * 64 + c0) * CH_ELEMS);

    // Prefetch channel 0.
    float4 pre[NLOAD];
#pragma unroll
    for (int k = 0; k < NLOAD; k++) {
        float4 v; v.x = 0.f; v.y = 0.f; v.z = 0.f; v.w = 0.f;
        if (g4off[k] >= 0) v = xb4[g4off[k]];
        pre[k] = v;
    }

    float2 acc[4][4];   // 4 output rows x 4 col-pairs (8 px)
#pragma unroll
    for (int o = 0; o < 4; o++)
#pragma unroll
        for (int q = 0; q < 4; q++) { acc[o][q].x = 0.f; acc[o][q].y = 0.f; }

#pragma unroll 1
    for (int c = 0; c < CPB; c++) {
        uint32_t* bufc = lds[c & 1];

        // Stage channel c (bf16-packed) into this half of the double buffer.
#pragma unroll
        for (int k = 0; k < NLOAD; k++) {
            if (k < 8 || tid < (NSLOT - 8 * TB)) {
                uint2 u;
                u.x = pk_bf16(pre[k].x, pre[k].y);
                u.y = pk_bf16(pre[k].z, pre[k].w);
                *(uint2*)&bufc[ldso[k]] = u;
            }
        }
        __syncthreads();
        // Single barrier per channel is safe: next iteration writes the OTHER
        // buffer, and re-writes of THIS buffer (c+2) sit behind barrier(c+1).

        // Prefetch channel c+1 (latency hidden under compute below).
        if (c + 1 < CPB) {
            const float4* xn4 = xb4 + (size_t)(c + 1) * (CH_ELEMS / 4);
#pragma unroll
            for (int k = 0; k < NLOAD; k++) {
                float4 v; v.x = 0.f; v.y = 0.f; v.z = 0.f; v.w = 0.f;
                if (g4off[k] >= 0) v = xn4[g4off[k]];
                pre[k] = v;
            }
        }

        // Weights for this channel (wave-uniform -> scalar loads).
        const float* wc = w + (size_t)(c0 + c) * 49;
        float wv[7][7];
#pragma unroll
        for (int dh = 0; dh < 7; dh++)
#pragma unroll
            for (int dw = 0; dw < 7; dw++) wv[dh][dw] = wc[dh * 7 + dw];

        // Compute: thread's output rows are 4*ty+o (o=0..3), cols 8*tx+p (p=0..7).
        // Sliding over 10 input rows; window = 16 bf16 = 2 x ds_read_b128.
#pragma unroll
        for (int k = 0; k < 10; k++) {
            const uint32_t* rp = &bufc[ROW_DW * (4 * ty + k) + 4 * tx];
            uint4 A = *(const uint4*)rp;
            uint4 B = *(const uint4*)(rp + 4);
            uint32_t W[8] = {A.x, A.y, A.z, A.w, B.x, B.y, B.z, B.w};
            // E[d] = (v[2d], v[2d+1]); O[d] = (v[2d+1], v[2d+2]); v[i] = col 8tx-4+i
            float2 E[8], O[7];
#pragma unroll
            for (int d = 0; d < 8; d++) { E[d].x = bf_lo(W[d]); E[d].y = bf_hi(W[d]); }
#pragma unroll
            for (int d = 0; d < 7; d++) { O[d].x = E[d].y; O[d].y = E[d + 1].x; }

#pragma unroll
            for (int o = 0; o < 4; o++) {
                const int dh = k - o;
                if (dh < 0 || dh > 6) continue;   // compile-time folded
#pragma unroll
                for (int q = 0; q < 4; q++) {
#pragma unroll
                    for (int dw = 0; dw < 7; dw++) {
                        const int j = 2 * q + dw + 1;   // pair (v[j], v[j+1])
                        float2 vp = (j & 1) ? O[j >> 1] : E[j >> 1];
                        acc[o][q] = pkfma(vp, wv[dh][dw], acc[o][q]);
                    }
                }
            }
        }
    }

    // Epilogue: one bias add (cs==0 block) + fp32 atomics (4 partials/output).
    const float bv = (cs == 0) ? bias[0] : 0.f;
    float* ob = out + (size_t)b * CH_ELEMS + (size_t)(row0 + 4 * ty) * WIMG + 8 * tx;
#pragma unroll
    for (int o = 0; o < 4; o++)
#pragma unroll
        for (int q = 0; q < 4; q++) {
            atomicAdd(&ob[o * WIMG + 2 * q],     acc[o][q].x + bv);
            atomicAdd(&ob[o * WIMG + 2 * q + 1], acc[o][q].y + bv);
        }
}

extern "C" void kernel_launch(void* const* d_in, const int* in_sizes, int n_in,
                              void* d_out, int out_size, void* d_ws, size_t ws_size,
                              hipStream_t stream) {
    const float* x    = (const float*)d_in[0];   // (64,64,128,128)
    const float* w    = (const float*)d_in[1];   // (64,7,7)
    const float* bias = (const float*)d_in[2];   // (1,)
    float* out        = (float*)d_out;           // (64,128,128)

    hipMemsetAsync(d_out, 0, (size_t)out_size * sizeof(float), stream);
    hipLaunchKernelGGL(conv7x7_v2, dim3(512), dim3(TB), 0, stream, x, w, bias, out);
}

// Round 3
// 379.190 us; speedup vs baseline: 1.2687x; 1.1965x over previous
//
#include <hip/hip_runtime.h>
#include <stdint.h>

// ConvolutionN: B=64, C=64, H=W=128, K=7, PAD=3, one output channel, fp32.
// v3: MFMA row-decomposition.
//   P[r, ow, dh] = sum_{c,dw} x_bf16[c, r, ow+dw-3] * w_bf16[c, dh, dw]
//     -> 16x16x32 bf16 MFMA GEMM per input row: M=ow(128), N=dh(7 of 16), K=(dw,c)=448
//   out[oh, ow] = bias + sum_{dh=0..6} P[oh+dh-3, ow, dh]   (LDS ring drain)
// Block = (batch, 16-row band): 22 P-rows, P in 8-slot LDS ring, x rows staged
// bf16 in LDS layout [col][c] (stride 36 dw). 512 blocks, 2/CU, ~68 KB LDS.

typedef short bf16x8 __attribute__((ext_vector_type(8)));
typedef float f32x4 __attribute__((ext_vector_type(4)));

#define HB    16
#define NR    22            // HB + 6 P-rows per band
#define XS    36            // dwords per col slot: 64 bf16 c's = 32 dw + 4 pad
#define XCOLS 134           // cols -3..130 stored at +3
#define XBUF  (XCOLS * XS)  // 4824 dw per buffer
#define RROW  132           // ring row stride (dw)
#define RING_DW (8 * 7 * RROW)

__device__ __forceinline__ uint32_t pk2bf(float a, float b) {
    // low16 = bf16_rne(a), high16 = bf16_rne(b)
    uint32_t ua = __builtin_bit_cast(uint32_t, a);
    uint32_t ub = __builtin_bit_cast(uint32_t, b);
    ua += 0x7FFFu + ((ua >> 16) & 1u);
    ub += 0x7FFFu + ((ub >> 16) & 1u);
    return (ua >> 16) | (ub & 0xFFFF0000u);
}

__global__ __launch_bounds__(256, 2)
void conv_mfma(const float* __restrict__ x, const float* __restrict__ w,
               const float* __restrict__ bias, float* __restrict__ out) {
    __shared__ uint32_t xlds[2][XBUF];     // 38592 B
    __shared__ float    ring[RING_DW];     // 29568 B

    const int tid  = threadIdx.x;
    const int lane = tid & 63;
    const int wv   = tid >> 6;             // wave 0..3 -> M-tiles {2wv, 2wv+1}
    const int b    = blockIdx.x >> 3;
    const int h0   = (blockIdx.x & 7) * HB;
    const int r0   = h0 - 3;

    const int nl = lane & 15;              // MFMA: A-row m / B-col n / C-col n
    const int q  = lane >> 4;              // quad

    // ---- zero halo cols (cols 0,1,2 and 131,132,133 of both x buffers) ----
    for (int i = tid; i < 2 * 6 * XS; i += 256) {
        int bi   = i / (6 * XS);
        int rem  = i - bi * (6 * XS);
        int colh = rem / XS;
        int dwi  = rem - colh * XS;
        int col  = (colh < 3) ? colh : (128 + colh);  // 0,1,2,131,132,133
        xlds[bi][col * XS + dwi] = 0u;
    }

    // ---- B fragments: Bf[kk][k=8q+j][n=nl] = w_bf16[c, dh=nl, dw], k=(dw,c) ----
    bf16x8 Bf[14];
#pragma unroll
    for (int kk = 0; kk < 14; kk++) {
        const int dw = kk >> 1, c0 = (kk & 1) * 32;
        bf16x8 f;
#pragma unroll
        for (int j = 0; j < 8; j++) {
            float v = (nl < 7) ? w[(c0 + 8 * q + j) * 49 + nl * 7 + dw] : 0.f;
            uint32_t u = __builtin_bit_cast(uint32_t, v);
            u += 0x7FFFu + ((u >> 16) & 1u);
            f[j] = (short)(u >> 16);
        }
        Bf[kk] = f;
    }

    // ---- staging geometry: thread covers 8 c's x 4 cols ----
    const int colq = tid & 31;             // col-quad 0..31 -> cols 4colq..+3
    const int cb   = (tid >> 5) * 8;       // c-base 0,8,..,56
    const float4* xp = (const float4*)x + (size_t)b * 262144;  // b * 64*16384/4

    float4 pre[8];
    {   // prefetch row r0 (guarded; OOB rows -> zeros)
        const bool v = ((unsigned)r0 < 128u);
        const int base = r0 * 32 + colq;
#pragma unroll
        for (int i = 0; i < 8; i++) {
            float4 g = {0.f, 0.f, 0.f, 0.f};
            if (v) g = xp[(cb + i) * 4096 + base];
            pre[i] = g;
        }
    }

    const float bv = bias[0];
    const int m = nl;                      // A-operand row index

#pragma unroll 1
    for (int it = 0; it < NR; it++) {
        const int r = r0 + it;
        uint32_t* buf = xlds[it & 1];

        // ---- stage row r: pack to bf16, transpose-write [col][c], 4x b128 ----
        float fa[8][4];
#pragma unroll
        for (int i = 0; i < 8; i++) {
            fa[i][0] = pre[i].x; fa[i][1] = pre[i].y;
            fa[i][2] = pre[i].z; fa[i][3] = pre[i].w;
        }
#pragma unroll
        for (int j = 0; j < 4; j++) {
            uint4 u;
            u.x = pk2bf(fa[0][j], fa[1][j]);
            u.y = pk2bf(fa[2][j], fa[3][j]);
            u.z = pk2bf(fa[4][j], fa[5][j]);
            u.w = pk2bf(fa[6][j], fa[7][j]);
            *(uint4*)&buf[(4 * colq + j + 3) * XS + (cb >> 1)] = u;
        }
        __syncthreads();   // staged row visible; halo zeros visible (it==0)

        // ---- prefetch row r+1 ----
        if (it + 1 < NR) {
            const int rn = r + 1;
            const bool v = ((unsigned)rn < 128u);
            const int base = rn * 32 + colq;
#pragma unroll
            for (int i = 0; i < 8; i++) {
                float4 g = {0.f, 0.f, 0.f, 0.f};
                if (v) g = xp[(cb + i) * 4096 + base];
                pre[i] = g;
            }
        }

        // ---- MFMA: P[r] for this wave's 2 M-tiles ----
        f32x4 acc0 = {0.f, 0.f, 0.f, 0.f};
        f32x4 acc1 = {0.f, 0.f, 0.f, 0.f};
#pragma unroll
        for (int kk = 0; kk < 14; kk++) {
            const int dw  = kk >> 1;
            const int c0h = (kk & 1) * 16;
            const uint32_t* a0 = &buf[(32 * wv + m + dw) * XS + c0h + 4 * q];
            uint4 A0 = *(const uint4*)a0;
            uint4 A1 = *(const uint4*)(a0 + 16 * XS);
            acc0 = __builtin_amdgcn_mfma_f32_16x16x32_bf16(
                       __builtin_bit_cast(bf16x8, A0), Bf[kk], acc0, 0, 0, 0);
            acc1 = __builtin_amdgcn_mfma_f32_16x16x32_bf16(
                       __builtin_bit_cast(bf16x8, A1), Bf[kk], acc1, 0, 0, 0);
        }

        // ---- write P C-frags to ring: lane holds n=nl, m=4q+reg -> j consecutive
        if (nl < 7) {
            const int slot = (r + 8) & 7;
            float* dst = &ring[(slot * 7 + nl) * RROW + 32 * wv + 4 * q];
            *(f32x4*)dst = acc0;
            *(f32x4*)(dst + 16) = acc1;
        }
        __syncthreads();   // P[r] visible

        // ---- drain out-row oh = r-3 ----
        const int oh = r - 3;
        if (oh >= h0 && tid < 128) {       // oh < h0+HB guaranteed (oh <= r1-3)
            float s = bv;
#pragma unroll
            for (int dh = 0; dh < 7; dh++) {
                const int pr = oh + dh - 3;
                s += ring[(((pr + 8) & 7) * 7 + dh) * RROW + tid];
            }
            out[b * 16384 + oh * 128 + tid] = s;
        }
    }
}

extern "C" void kernel_launch(void* const* d_in, const int* in_sizes, int n_in,
                              void* d_out, int out_size, void* d_ws, size_t ws_size,
                              hipStream_t stream) {
    const float* x    = (const float*)d_in[0];   // (64,64,128,128)
    const float* w    = (const float*)d_in[1];   // (64,7,7)
    const float* bias = (const float*)d_in[2];   // (1,)
    float* out        = (float*)d_out;           // (64,128,128)

    hipLaunchKernelGGL(conv_mfma, dim3(512), dim3(256), 0, stream, x, w, bias, out);
}